// Round 5
// baseline (343.935 us; speedup 1.0000x reference)
//
#include <hip/hip_runtime.h>

// GIN 2-layer forward, MI355X (gfx950). Round 16:
//  - gather rebuilt around WIDE loads: lane owns 8 channels (16B dwordx4),
//    16 lanes cover one 256B row, one wave-instruction gathers 4 rows
//    (1KB). 4x fewer load instructions, 4x more bytes per vmcnt slot than
//    the round-11 4B/lane form (which measured ~1 outstanding row/wave).
//    Cross-lgroup combine via shfl_xor(16/32); lgroup 0 writes the row.
//  - binA parallelism fixed: 128 -> 800 blocks (1000 edges each). Round-4
//    counters: 56us at 4.3% occupancy, 0.8% VALU = starvation, not work.
//  - everything else identical to round 15.

#define N_NODES 50000
#define N_EDGES 800000
#define DIM 128
#define BN_EPS 1e-5f
#define GEMM_GRID 782           // ceil(N_NODES/64)
#define NBUCK 256
#define NPB 196                 // nodes per bucket
#define BCAP 4096               // max edges per bucket
#define BINA_BLOCKS 800
#define EPB 1000                // 800 * 1000 = 800000 exact
#define CBLK 12500              // col-block width (kept, perf-neutral)
#define NSLOT 16                // stats atomic slots

using bfrag8 = __attribute__((ext_vector_type(8))) short;
using accf4  = __attribute__((ext_vector_type(4))) float;

__device__ __forceinline__ float bf2f(unsigned short u) {
  union { unsigned u32; float f; } c;
  c.u32 = ((unsigned)u) << 16;
  return c.f;
}
__device__ __forceinline__ unsigned short f2bf(float f) {
  union { float f; unsigned u32; } c;
  c.f = f;
  unsigned u = c.u32;
  return (unsigned short)((u + 0x7fffu + ((u >> 16) & 1u)) >> 16);  // RNE
}

// ---- prep: detect dtype, pack weights, convert vectors, zero scratch ----
struct PPtrs { const void* xs; const void* w[4]; const void* v[10]; };

__global__ __launch_bounds__(256) void prep_kernel(
    PPtrs pp, unsigned short* __restrict__ PW, float* __restrict__ PV,
    int* __restrict__ flag, float* __restrict__ ps2, int* __restrict__ deg) {
  __shared__ int oks[64];
  __shared__ int bfs;
  int t = threadIdx.x;
  if (t < 64) {
    unsigned short u = ((const unsigned short*)pp.xs)[t * 2];
    int e = (u >> 7) & 0xFF;
    oks[t] = ((e >= 96 && e <= 134) || ((u & 0x7FFFu) == 0)) ? 1 : 0;
  }
  __syncthreads();
  if (t == 0) {
    int c = 0;
    for (int i = 0; i < 64; ++i) c += oks[i];
    bfs = (c >= 56) ? 1 : 0;
  }
  __syncthreads();
  int bf = bfs;
  int b = blockIdx.x;

  if (b < 4) {
    const void* src = pp.w[b];
    unsigned short* dst = PW + (size_t)b * 16384;
    for (int f = t; f < 2048; f += 256) {
      int kt = f >> 9, nt = (f >> 6) & 7, lane = f & 63;
      int kbase = kt * 32 + (lane >> 4) * 8;
      int n = nt * 16 + (lane & 15);
      unsigned short tmp[8];
      for (int j = 0; j < 8; ++j) {
        int idx = (kbase + j) * DIM + n;
        if (bf) tmp[j] = ((const unsigned short*)src)[idx];
        else    tmp[j] = f2bf(((const float*)src)[idx]);
      }
      for (int j = 0; j < 8; ++j) dst[f * 8 + j] = tmp[j];
    }
  } else if (b == 4) {
    for (int j = t; j < 10 * DIM; j += 256) {
      int vec = j >> 7, idx = j & 127;
      float v;
      if (bf) v = bf2f(((const unsigned short*)pp.v[vec])[idx]);
      else    v = ((const float*)pp.v[vec])[idx];
      PV[j] = v;
    }
    if (t == 0) *flag = bf;
    for (int j = t; j < 3 * NSLOT * 256; j += 256) ps2[j] = 0.f;
  } else {
    const int total = N_NODES + NBUCK;
    for (int i = (b - 5) * 256 + t; i < total; i += 35 * 256) deg[i] = 0;
  }
}

// ================= CSR build =================
__global__ __launch_bounds__(256) void binA_kernel(
    const int* __restrict__ row, const int* __restrict__ col,
    int* __restrict__ deg, int* __restrict__ bcnt, uint2* __restrict__ ebuf) {
  __shared__ int hist[NBUCK];
  __shared__ int base[NBUCK];
  int t = threadIdx.x;
  int e0 = blockIdx.x * EPB;
  hist[t] = 0;
  __syncthreads();
  for (int i = t; i < EPB; i += 256) {
    int r = row[e0 + i];
    atomicAdd(&deg[r], 1);
    atomicAdd(&hist[r / NPB], 1);
  }
  __syncthreads();
  base[t] = atomicAdd(&bcnt[t], hist[t]);
  hist[t] = 0;
  __syncthreads();
  for (int i = t; i < EPB; i += 256) {
    int r = row[e0 + i];
    int c = col[e0 + i];
    int b = r / NPB;
    int rank = atomicAdd(&hist[b], 1);
    ebuf[(size_t)b * BCAP + base[b] + rank] = make_uint2((unsigned)r, (unsigned)c);
  }
}

// binB: per-block redundant scan of bcnt -> segbase; local degree scan ->
// offs; col-block-ordered scatter into csr_col.
__global__ __launch_bounds__(256) void binB_kernel(
    const int* __restrict__ deg, const int* __restrict__ bcnt,
    const uint2* __restrict__ ebuf, int* __restrict__ csr_col,
    int* __restrict__ offs) {
  __shared__ int sc[256];
  __shared__ int dg[256];
  __shared__ int cur4[NPB * 4];
  __shared__ int seg[BCAP];
  int b = blockIdx.x;
  int t = threadIdx.x;

  sc[t] = bcnt[t];
  __syncthreads();
  for (int d = 1; d < 256; d <<= 1) {
    int v = (t >= d) ? sc[t - d] : 0;
    __syncthreads();
    sc[t] += v;
    __syncthreads();
  }
  int segbase = (b == 0) ? 0 : sc[b - 1];

  int nb = b * NPB;
  int nend = nb + NPB;
  if (nend > N_NODES) nend = N_NODES;
  int nn = nend - nb;

  int myd = (t < nn) ? deg[nb + t] : 0;
  dg[t] = myd;
  __syncthreads();
  for (int d = 1; d < 256; d <<= 1) {
    int v = (t >= d) ? dg[t - d] : 0;
    __syncthreads();
    dg[t] += v;
    __syncthreads();
  }
  int excl = dg[t] - myd;
  if (t < nn) offs[nb + t] = segbase + excl;
  if (b == NBUCK - 1 && t == 0) offs[N_NODES] = N_EDGES;

  int cnt = bcnt[b];
  const uint2* eb = ebuf + (size_t)b * BCAP;
  for (int i = t; i < nn * 4; i += 256) cur4[i] = 0;
  __syncthreads();
  for (int i = t; i < cnt; i += 256) {
    uint2 e = eb[i];
    int blk = (int)e.y / CBLK;
    atomicAdd(&cur4[(e.x - (unsigned)nb) * 4 + blk], 1);
  }
  __syncthreads();
  if (t < nn) {
    int run = excl;
    int c0 = cur4[t * 4 + 0], c1 = cur4[t * 4 + 1];
    int c2 = cur4[t * 4 + 2];
    cur4[t * 4 + 0] = run;
    cur4[t * 4 + 1] = run + c0;
    cur4[t * 4 + 2] = run + c0 + c1;
    cur4[t * 4 + 3] = run + c0 + c1 + c2;
  }
  __syncthreads();
  for (int i = t; i < cnt; i += 256) {
    uint2 e = eb[i];
    int blk = (int)e.y / CBLK;
    int slot = atomicAdd(&cur4[(e.x - (unsigned)nb) * 4 + blk], 1);
    seg[slot] = (int)e.y;
  }
  __syncthreads();
  for (int i = t; i < cnt; i += 256)
    csr_col[segbase + i] = seg[i];
}

// ================= wide-load gather =================
// Lane owns 8 channels (16B). 16 lanes = one 256B row; the 4 lane-groups
// of a wave each own every-4th edge => one dwordx4 wave-instruction
// gathers 4 rows (1KB). Main loop: 4 loads = 16 edges in flight (4KB).
// Combine lane-groups with shfl_xor(16/32); lgroup 0 stores the row.
// mode 0: plain sum; mode 1: relu(v*sc+sh) from slotted stats + g/be.
#define ACC8_SUM(U) {                                        \
  acc[0] += bf2f((unsigned short)((U).x));                   \
  acc[1] += bf2f((unsigned short)((U).x >> 16));             \
  acc[2] += bf2f((unsigned short)((U).y));                   \
  acc[3] += bf2f((unsigned short)((U).y >> 16));             \
  acc[4] += bf2f((unsigned short)((U).z));                   \
  acc[5] += bf2f((unsigned short)((U).z >> 16));             \
  acc[6] += bf2f((unsigned short)((U).w));                   \
  acc[7] += bf2f((unsigned short)((U).w >> 16)); }

#define ACC8_BN(U) {                                                      \
  acc[0] += fmaxf(bf2f((unsigned short)((U).x)) * sc[0] + sh[0], 0.f);    \
  acc[1] += fmaxf(bf2f((unsigned short)((U).x >> 16)) * sc[1] + sh[1], 0.f); \
  acc[2] += fmaxf(bf2f((unsigned short)((U).y)) * sc[2] + sh[2], 0.f);    \
  acc[3] += fmaxf(bf2f((unsigned short)((U).y >> 16)) * sc[3] + sh[3], 0.f); \
  acc[4] += fmaxf(bf2f((unsigned short)((U).z)) * sc[4] + sh[4], 0.f);    \
  acc[5] += fmaxf(bf2f((unsigned short)((U).z >> 16)) * sc[5] + sh[5], 0.f); \
  acc[6] += fmaxf(bf2f((unsigned short)((U).w)) * sc[6] + sh[6], 0.f);    \
  acc[7] += fmaxf(bf2f((unsigned short)((U).w >> 16)) * sc[7] + sh[7], 0.f); }

__global__ __launch_bounds__(256, 4) void gather_row_kernel(
    const void* __restrict__ src, const int* __restrict__ offs,
    const int* __restrict__ csr_col, const float* __restrict__ stats_in,
    const float* __restrict__ gv, const float* __restrict__ bev,
    unsigned short* __restrict__ agg, const int* __restrict__ flagp,
    int mode) {
  __shared__ float ssl[256];
  int tid = threadIdx.x;
  if (mode == 1) {
    if (tid < 128) {
      float s = 0.f, q = 0.f;
#pragma unroll
      for (int k = 0; k < NSLOT; ++k) {
        s += stats_in[k * 256 + tid];
        q += stats_in[k * 256 + 128 + tid];
      }
      const float invN = 1.0f / (float)N_NODES;
      float m = s * invN;
      float v = q * invN - m * m;
      float scv = gv[tid] * rsqrtf(v + BN_EPS);
      ssl[tid] = scv;
      ssl[128 + tid] = bev[tid] - m * scv;
    }
    __syncthreads();
  }

  int node = blockIdx.x * 4 + (tid >> 6);
  if (node >= N_NODES) return;
  int lane = tid & 63;
  int start = offs[node], end = offs[node + 1];
  int bf = *flagp;

  if (mode == 1 || bf) {
    const int lgroup = lane >> 4;     // 0..3: edge phase
    const int lidx = lane & 15;       // 16 lanes span the 256B row
    const int ch = lidx * 8;          // 8 bf16 channels per lane
    const unsigned short* h = (const unsigned short*)src;
    float acc[8];
#pragma unroll
    for (int k = 0; k < 8; ++k) acc[k] = 0.f;
    float sc[8], sh[8];
    if (mode == 1) {
#pragma unroll
      for (int k = 0; k < 8; ++k) {
        sc[k] = ssl[ch + k];
        sh[k] = ssl[128 + ch + k];
      }
    }

    int j = start;
    if (mode == 1) {
      for (; j + 15 < end; j += 16) {
        uint4 u0 = *(const uint4*)(h + (size_t)csr_col[j + 0 + lgroup] * DIM + ch);
        uint4 u1 = *(const uint4*)(h + (size_t)csr_col[j + 4 + lgroup] * DIM + ch);
        uint4 u2 = *(const uint4*)(h + (size_t)csr_col[j + 8 + lgroup] * DIM + ch);
        uint4 u3 = *(const uint4*)(h + (size_t)csr_col[j + 12 + lgroup] * DIM + ch);
        ACC8_BN(u0); ACC8_BN(u1); ACC8_BN(u2); ACC8_BN(u3);
      }
      for (; j + 3 < end; j += 4) {
        uint4 u = *(const uint4*)(h + (size_t)csr_col[j + lgroup] * DIM + ch);
        ACC8_BN(u);
      }
      if (lgroup < end - j) {
        uint4 u = *(const uint4*)(h + (size_t)csr_col[j + lgroup] * DIM + ch);
        ACC8_BN(u);
      }
    } else {
      for (; j + 15 < end; j += 16) {
        uint4 u0 = *(const uint4*)(h + (size_t)csr_col[j + 0 + lgroup] * DIM + ch);
        uint4 u1 = *(const uint4*)(h + (size_t)csr_col[j + 4 + lgroup] * DIM + ch);
        uint4 u2 = *(const uint4*)(h + (size_t)csr_col[j + 8 + lgroup] * DIM + ch);
        uint4 u3 = *(const uint4*)(h + (size_t)csr_col[j + 12 + lgroup] * DIM + ch);
        ACC8_SUM(u0); ACC8_SUM(u1); ACC8_SUM(u2); ACC8_SUM(u3);
      }
      for (; j + 3 < end; j += 4) {
        uint4 u = *(const uint4*)(h + (size_t)csr_col[j + lgroup] * DIM + ch);
        ACC8_SUM(u);
      }
      if (lgroup < end - j) {
        uint4 u = *(const uint4*)(h + (size_t)csr_col[j + lgroup] * DIM + ch);
        ACC8_SUM(u);
      }
    }

    // combine the 4 lane-groups (each summed every-4th edge)
#pragma unroll
    for (int k = 0; k < 8; ++k) {
      acc[k] += __shfl_xor(acc[k], 16, 64);
      acc[k] += __shfl_xor(acc[k], 32, 64);
    }
    if (lgroup == 0) {
      uint4 o;
      o.x = (unsigned)f2bf(acc[0]) | ((unsigned)f2bf(acc[1]) << 16);
      o.y = (unsigned)f2bf(acc[2]) | ((unsigned)f2bf(acc[3]) << 16);
      o.z = (unsigned)f2bf(acc[4]) | ((unsigned)f2bf(acc[5]) << 16);
      o.w = (unsigned)f2bf(acc[6]) | ((unsigned)f2bf(acc[7]) << 16);
      *(uint4*)(agg + (size_t)node * DIM + ch) = o;
    }
  } else {
    // fp32 input fallback (cold path in this bench): lane owns 2 channels
    const float* x = (const float*)src;
    int ch = lane * 2;
    float a0 = 0.f, a1 = 0.f;
    int j = start;
    for (; j + 7 < end; j += 8) {
      int ix[8];
#pragma unroll
      for (int k = 0; k < 8; ++k) ix[k] = csr_col[j + k];
#pragma unroll
      for (int k = 0; k < 8; ++k) {
        float2 v = *(const float2*)(x + (size_t)ix[k] * DIM + ch);
        a0 += v.x; a1 += v.y;
      }
    }
    for (; j < end; ++j) {
      float2 v = *(const float2*)(x + (size_t)csr_col[j] * DIM + ch);
      a0 += v.x; a1 += v.y;
    }
    unsigned o = (unsigned)f2bf(a0) | ((unsigned)f2bf(a1) << 16);
    *(unsigned*)(agg + (size_t)node * DIM + ch) = o;
  }
}

// ================= MFMA GEMM (+BN transform in, +slotted stats out) ======
__global__ __launch_bounds__(256) void gemm_kernel(
    const void* __restrict__ Ap, const unsigned short* __restrict__ agg,
    const unsigned short* __restrict__ PWm, const float* __restrict__ bias,
    const float* __restrict__ stats_in, const float* __restrict__ gv,
    const float* __restrict__ bev, void* __restrict__ Cp,
    float* __restrict__ stats_out, const int* __restrict__ flagp,
    int a_ext, int add_agg, int out_ext) {
  __shared__ unsigned short As[64 * 136];
  __shared__ float red_s[256];
  __shared__ float red_q[256];
  __shared__ float ssl[256];
  const int tid = threadIdx.x;
  const int row0 = blockIdx.x * 64;
  const int bf = *flagp;
  const int has_tf = (stats_in != nullptr);

  if (has_tf) {
    if (tid < 128) {
      float s = 0.f, q = 0.f;
#pragma unroll
      for (int k = 0; k < NSLOT; ++k) {
        s += stats_in[k * 256 + tid];
        q += stats_in[k * 256 + 128 + tid];
      }
      const float invN = 1.0f / (float)N_NODES;
      float m = s * invN;
      float v = q * invN - m * m;
      float scv = gv[tid] * rsqrtf(v + BN_EPS);
      ssl[tid] = scv;
      ssl[128 + tid] = bev[tid] - m * scv;
    }
    __syncthreads();
  }

  for (int i = 0; i < 8; ++i) {
    int G = tid + i * 256;
    int lrow = G >> 5;
    int ch = (G & 31) * 4;
    int grow = row0 + lrow;
    float4 v = make_float4(0.f, 0.f, 0.f, 0.f);
    if (grow < N_NODES) {
      if (a_ext && !bf) {
        v = *(const float4*)((const float*)Ap + (size_t)grow * DIM + ch);
      } else {
        ushort4 u = *(const ushort4*)((const unsigned short*)Ap +
                                      (size_t)grow * DIM + ch);
        v = make_float4(bf2f(u.x), bf2f(u.y), bf2f(u.z), bf2f(u.w));
      }
      if (has_tf) {
        float4 sc = *(const float4*)&ssl[ch];
        float4 sh = *(const float4*)&ssl[128 + ch];
        v.x = fmaxf(v.x * sc.x + sh.x, 0.f);
        v.y = fmaxf(v.y * sc.y + sh.y, 0.f);
        v.z = fmaxf(v.z * sc.z + sh.z, 0.f);
        v.w = fmaxf(v.w * sc.w + sh.w, 0.f);
      }
      if (add_agg) {
        ushort4 au = *(const ushort4*)(agg + (size_t)grow * DIM + ch);
        v.x += bf2f(au.x); v.y += bf2f(au.y);
        v.z += bf2f(au.z); v.w += bf2f(au.w);
      }
    }
    ushort4 o;
    o.x = f2bf(v.x); o.y = f2bf(v.y); o.z = f2bf(v.z); o.w = f2bf(v.w);
    *(ushort4*)&As[lrow * 136 + ch] = o;
  }
  __syncthreads();

  const int wv = tid >> 6, lane = tid & 63;
  const int quad = lane >> 4, lo = lane & 15;
  accf4 acc[8];
#pragma unroll
  for (int nt = 0; nt < 8; ++nt) {
    acc[nt][0] = 0.f; acc[nt][1] = 0.f; acc[nt][2] = 0.f; acc[nt][3] = 0.f;
  }
#pragma unroll
  for (int kt = 0; kt < 4; ++kt) {
    bfrag8 a = *(const bfrag8*)&As[(wv * 16 + lo) * 136 + kt * 32 + quad * 8];
    const unsigned short* pw = PWm + kt * 4096 + lane * 8;
#pragma unroll
    for (int nt = 0; nt < 8; ++nt) {
      bfrag8 b = *(const bfrag8*)(pw + nt * 512);
      acc[nt] = __builtin_amdgcn_mfma_f32_16x16x32_bf16(a, b, acc[nt], 0, 0, 0);
    }
  }
  __syncthreads();

  if (out_ext && !bf) {
    float* Co = (float*)Cp;
#pragma unroll
    for (int nt = 0; nt < 8; ++nt) {
      float b = bias[nt * 16 + lo];
#pragma unroll
      for (int reg = 0; reg < 4; ++reg) {
        int grow = row0 + wv * 16 + quad * 4 + reg;
        if (grow < N_NODES)
          Co[(size_t)grow * DIM + nt * 16 + lo] = acc[nt][reg] + b;
      }
    }
  } else {
#pragma unroll
    for (int nt = 0; nt < 8; ++nt) {
      float b = bias[nt * 16 + lo];
#pragma unroll
      for (int reg = 0; reg < 4; ++reg) {
        As[(wv * 16 + quad * 4 + reg) * 136 + nt * 16 + lo] =
            f2bf(acc[nt][reg] + b);
      }
    }
    __syncthreads();
    unsigned short* Co = (unsigned short*)Cp;
    for (int i = 0; i < 8; ++i) {
      int G = tid + i * 256;
      int lrow = G >> 5, ch = (G & 31) * 4;
      int grow = row0 + lrow;
      if (grow < N_NODES)
        *(ushort4*)(Co + (size_t)grow * DIM + ch) =
            *(const ushort4*)&As[lrow * 136 + ch];
    }
    if (stats_out) {
      int c = tid & 127, rh = tid >> 7;
      int rmax = N_NODES - row0;
      if (rmax > 64) rmax = 64;
      int rend = rh * 32 + 32;
      if (rend > rmax) rend = rmax;
      float s = 0.f, q = 0.f;
      for (int r = rh * 32; r < rend; ++r) {
        float v = bf2f(As[r * 136 + c]);
        s += v; q += v * v;
      }
      red_s[tid] = s; red_q[tid] = q;
      __syncthreads();
      if (tid < 128) {
        float* so = stats_out + (size_t)(blockIdx.x & (NSLOT - 1)) * 256;
        atomicAdd(so + tid, red_s[tid] + red_s[tid + 128]);
        atomicAdd(so + 128 + tid, red_q[tid] + red_q[tid + 128]);
      }
    }
  }
}

extern "C" void kernel_launch(void* const* d_in, const int* in_sizes, int n_in,
                              void* d_out, int out_size, void* d_ws, size_t ws_size,
                              hipStream_t stream) {
  const void* x  = d_in[0];
  const int* row = (const int*)d_in[1];
  const int* col = (const int*)d_in[2];

  const size_t ND = (size_t)N_NODES * DIM;
  unsigned short* agg = (unsigned short*)d_ws;        // ND bf16
  unsigned short* hA  = agg + ND;                     // ND bf16
  unsigned short* hB  = hA + ND;                      // ND bf16
  unsigned short* PW  = hB + ND;                      // 4*16384 bf16
  float* PV    = (float*)(PW + 4 * 16384);            // 10*128 fp32
  float* ps2   = PV + 10 * DIM;                       // 3*NSLOT*256 fp32
  int*   flag  = (int*)(ps2 + 3 * NSLOT * 256);       // 1 (+pad)
  int*   deg   = flag + 4;                            // N
  int*   bcnt  = deg + N_NODES;                       // NBUCK (contiguous!)
  int*   offs  = bcnt + NBUCK;                        // N+1
  int*   csr_col = offs + N_NODES + 1;                // E
  uint2* ebuf  = (uint2*)((((size_t)(csr_col + N_EDGES)) + 15) & ~(size_t)15);

  float* S0 = ps2 + 0 * NSLOT * 256;
  float* S1 = ps2 + 1 * NSLOT * 256;
  float* S2 = ps2 + 2 * NSLOT * 256;

  float* c0_b1f = PV + 0 * DIM; float* c0_gf  = PV + 1 * DIM;
  float* c0_bef = PV + 2 * DIM; float* c0_b2f = PV + 3 * DIM;
  float* bn0_gf = PV + 4 * DIM; float* bn0_bef= PV + 5 * DIM;
  float* c1_b1f = PV + 6 * DIM; float* c1_gf  = PV + 7 * DIM;
  float* c1_bef = PV + 8 * DIM; float* c1_b2f = PV + 9 * DIM;

  const int grow_grid = (N_NODES + 3) / 4;  // 12500

  PPtrs pp;
  pp.xs = x;
  pp.w[0] = d_in[3];  pp.w[1] = d_in[7];  pp.w[2] = d_in[11]; pp.w[3] = d_in[15];
  pp.v[0] = d_in[4];  pp.v[1] = d_in[5];  pp.v[2] = d_in[6];  pp.v[3] = d_in[8];
  pp.v[4] = d_in[9];  pp.v[5] = d_in[10]; pp.v[6] = d_in[12]; pp.v[7] = d_in[13];
  pp.v[8] = d_in[14]; pp.v[9] = d_in[16];

  // prep: detect + weights + vectors + flag + zero(ps2, deg, bcnt)
  prep_kernel<<<40, 256, 0, stream>>>(pp, PW, PV, flag, ps2, deg);

  // CSR build (2 dispatches)
  binA_kernel<<<BINA_BLOCKS, 256, 0, stream>>>(row, col, deg, bcnt, ebuf);
  binB_kernel<<<NBUCK, 256, 0, stream>>>(deg, bcnt, ebuf, csr_col, offs);

  // ---- conv0 ----
  gather_row_kernel<<<grow_grid, 256, 0, stream>>>(
      x, offs, csr_col, nullptr, nullptr, nullptr, agg, flag, 0);
  gemm_kernel<<<GEMM_GRID, 256, 0, stream>>>(
      x, agg, PW + 0 * 16384, c0_b1f, nullptr, nullptr, nullptr,
      hA, S0, flag, 1, 1, 0);
  gemm_kernel<<<GEMM_GRID, 256, 0, stream>>>(
      hA, nullptr, PW + 1 * 16384, c0_b2f, S0, c0_gf, c0_bef,
      hB, S1, flag, 0, 0, 0);

  // ---- conv1 ----
  gather_row_kernel<<<grow_grid, 256, 0, stream>>>(
      hB, offs, csr_col, S1, bn0_gf, bn0_bef, agg, flag, 1);
  gemm_kernel<<<GEMM_GRID, 256, 0, stream>>>(
      hB, agg, PW + 2 * 16384, c1_b1f, S1, bn0_gf, bn0_bef,
      hA, S2, flag, 0, 1, 0);
  gemm_kernel<<<GEMM_GRID, 256, 0, stream>>>(
      hA, nullptr, PW + 3 * 16384, c1_b2f, S2, c1_gf, c1_bef,
      d_out, nullptr, flag, 0, 0, 1);
}